// Round 11
// baseline (172.096 us; speedup 1.0000x reference)
//
#include <hip/hip_runtime.h>

// ---------------------------------------------------------------------------
// SelfAttention: B=2,T=2048,D_IN=1024,E=64,H=16, causal, interleaved (E,H)
// qh/kh: [b][t][h*64 + pi(e)] with pi(e)=(e&15)*4+(e>>4) applied to BOTH Q,K
//   (QK^T invariant). vh: [b][h][e][kappa(t)].
// gemm_qkv: 128x128 tile, 3-buffer counted-vmcnt pipeline, LINEAR LDS
//   (XOR swizzle reverted: regressed in BOTH regimes, rounds 3 & 10).
// attn: 128-row Q tiles; K/V now 3-BUFFER COUNTED-VMCNT (2 tiles in flight,
//   vmcnt(4)/iter) — same pattern that fixed gemm_qkv in round 8. 2 blocks/CU
//   (attn proven chain-bound, not occupancy-bound: rounds 5/6).
//   kappa-packed P, static-max softmax, 24-slot split grid; split partials
//   consumed directly by gemm_out (combine fused).
// ---------------------------------------------------------------------------

typedef __bf16 bf16x8 __attribute__((ext_vector_type(8)));
typedef __bf16 bf16x4 __attribute__((ext_vector_type(4)));
typedef float f32x4 __attribute__((ext_vector_type(4)));
typedef unsigned short u16;
typedef unsigned int u32;

#define AS1 __attribute__((address_space(1)))
#define AS3 __attribute__((address_space(3)))

__device__ __forceinline__ void gll16(const void* g, void* l) {
    __builtin_amdgcn_global_load_lds((const AS1 u32*)g, (AS3 u32*)l, 16, 0, 0);
}

__device__ __forceinline__ u16 f2bf(float f) {      // native cast (RNE, cvt_pk-pairable)
    __bf16 h = (__bf16)f;
    union { __bf16 h; u16 u; } v; v.h = h; return v.u;
}

#define MM 4096           // B*T
#define SCALE_LOG2E 0.18033688011112042f   // log2(e)/sqrt(64)

// ---------------- kernel 1: prep = cast_x (bid<4096) + transpose_w ----------------
__global__ void prep(const float* __restrict__ in, u16* __restrict__ out,
                     const float* __restrict__ Wq, const float* __restrict__ Wk,
                     const float* __restrict__ Wv, const float* __restrict__ Wu,
                     u16* __restrict__ wqt, u16* __restrict__ wkt,
                     u16* __restrict__ wvt, u16* __restrict__ wut) {
    __shared__ float lds[32][33];
    int bid = blockIdx.x, tid = threadIdx.x;
    if (bid < 4096) {                      // cast inp -> bf16, 1M float4
        int i = bid * 256 + tid;
        float4 f = ((const float4*)in)[i];
        bf16x4 o;
        o[0] = (__bf16)f.x; o[1] = (__bf16)f.y; o[2] = (__bf16)f.z; o[3] = (__bf16)f.w;
        ((bf16x4*)out)[i] = o;
        return;
    }
    int bid2 = bid - 4096;
    int z = bid2 >> 10, y = (bid2 >> 5) & 31, x = bid2 & 31;
    const float* src; u16* dst; int N;
    if (z == 0)      { src = Wq; dst = wqt; N = 1024; }
    else if (z == 1) { src = Wk; dst = wkt; N = 1024; }
    else if (z == 2) { src = Wv; dst = wvt; N = 1024; }
    else             { src = Wu; dst = wut; N = 64; if (y >= 2) return; }
    int k0 = x * 32, n0 = y * 32;
    int c = tid & 31, r0 = tid >> 5;
#pragma unroll
    for (int p = 0; p < 4; ++p) {
        int r = r0 + p * 8;
        lds[r][c] = src[(k0 + r) * N + n0 + c];
    }
    __syncthreads();
#pragma unroll
    for (int p = 0; p < 4; ++p) {
        int n = n0 + r0 + p * 8;
        if (z < 3) {
            int rnew = ((n & 15) << 6) | (n >> 4);
            dst[rnew * 1024 + k0 + c] = f2bf(lds[c][n - n0]);
        } else {
            int k = k0 + c;
            int kp = ((k & 15) << 6) | (k >> 4);       // h*64+e position
            dst[n * 1024 + kp] = f2bf(lds[c][n - n0]);
        }
    }
}

// ---------------- kernel 3: QKV GEMM, 3-buffer counted-vmcnt pipeline ----------------
// z=0: Q *SCALE -> [b][t][h*64+pi(e)]; z=1: K -> same (pi on both: S invariant);
// z=2: V -> [b][h][e][kappa(t)], kappa(u) = (u&15)*4 + (u>>4).
__global__ __launch_bounds__(256) void gemm_qkv(const u16* __restrict__ xb,
                                                const u16* __restrict__ wqt,
                                                const u16* __restrict__ wkt,
                                                const u16* __restrict__ wvt,
                                                u16* __restrict__ qh, u16* __restrict__ kh,
                                                u16* __restrict__ vh) {
    int z = blockIdx.z;
    const u16* wt = (z == 0) ? wqt : (z == 1) ? wkt : wvt;
    u16* dst      = (z == 0) ? qh  : (z == 1) ? kh  : vh;
    __shared__ u16 lA[3][128 * 32];
    __shared__ u16 lB[3][128 * 32];
    int tid = threadIdx.x;
    int m0 = blockIdx.x * 128, n0 = blockIdx.y * 128;
    int lane = tid & 63, w = tid >> 6;
    int wr = w >> 1, wc = w & 1;
    int l15 = lane & 15, quad = lane >> 4;
    f32x4 acc[4][4] = {};
    int srow = tid >> 2, scol = (tid & 3) * 8;
    const u16* ga = xb + (m0 + srow) * 1024 + scol;    // + pp*65536 + kb
    const u16* gb = wt + (n0 + srow) * 1024 + scol;
    // prologue: stage tiles 0 and 1
#pragma unroll
    for (int t0 = 0; t0 < 2; ++t0)
#pragma unroll
        for (int pp = 0; pp < 2; ++pp) {
            gll16(ga + pp * 65536 + t0 * 32, lA[t0] + (pp * 256 + tid) * 8);
            gll16(gb + pp * 65536 + t0 * 32, lB[t0] + (pp * 256 + tid) * 8);
        }
    int cur = 0;
#pragma unroll 1
    for (int kk = 0; kk < 32; ++kk) {
        if (kk < 31) asm volatile("s_waitcnt vmcnt(4)" ::: "memory");  // tile kk landed
        else         asm volatile("s_waitcnt vmcnt(0)" ::: "memory");
        __builtin_amdgcn_s_barrier();                  // all waves done with buf (kk+2)%3
        if (kk + 2 < 32) {                             // issue tile kk+2 (2 in flight)
            int nxt = cur + 2; if (nxt >= 3) nxt -= 3;
            int kb = (kk + 2) * 32;
#pragma unroll
            for (int pp = 0; pp < 2; ++pp) {
                gll16(ga + pp * 65536 + kb, lA[nxt] + (pp * 256 + tid) * 8);
                gll16(gb + pp * 65536 + kb, lB[nxt] + (pp * 256 + tid) * 8);
            }
        }
        bf16x8 af[4], bfr[4];
#pragma unroll
        for (int i = 0; i < 4; ++i)
            af[i] = *(const bf16x8*)(lA[cur] + (wr * 64 + i * 16 + l15) * 32 + quad * 8);
#pragma unroll
        for (int j = 0; j < 4; ++j)
            bfr[j] = *(const bf16x8*)(lB[cur] + (wc * 64 + j * 16 + l15) * 32 + quad * 8);
#pragma unroll
        for (int i = 0; i < 4; ++i)
#pragma unroll
            for (int j = 0; j < 4; ++j)
                acc[i][j] = __builtin_amdgcn_mfma_f32_16x16x32_bf16(af[i], bfr[j], acc[i][j], 0, 0, 0);
        ++cur; if (cur == 3) cur = 0;
    }
    int bb = m0 >> 11;
    int hb = (n0 >> 6) + wc;                   // head for this wave's n-half
    if (z < 2) {
        // pi-packed rows: column pi(j*16+l15) = l15*4+j -> bf16x4 per (i,r)
        float scale = (z == 0) ? SCALE_LOG2E : 1.f;
#pragma unroll
        for (int i = 0; i < 4; ++i)
#pragma unroll
            for (int r = 0; r < 4; ++r) {
                int m = m0 + wr * 64 + i * 16 + quad * 4 + r;
                bf16x4 o;
                o[0] = (__bf16)(acc[i][0][r] * scale); o[1] = (__bf16)(acc[i][1][r] * scale);
                o[2] = (__bf16)(acc[i][2][r] * scale); o[3] = (__bf16)(acc[i][3][r] * scale);
                *(bf16x4*)(dst + m * 1024 + hb * 64 + l15 * 4) = o;
            }
    } else {
        // kappa-packed V: pack i (t stride 16) -> contiguous kappa positions
#pragma unroll
        for (int j = 0; j < 4; ++j)
#pragma unroll
            for (int r = 0; r < 4; ++r) {
                bf16x4 o;
                o[0] = (__bf16)acc[0][j][r]; o[1] = (__bf16)acc[1][j][r];
                o[2] = (__bf16)acc[2][j][r]; o[3] = (__bf16)acc[3][j][r];
                *(bf16x4*)(dst + (((bb * 16 + hb) * 64) + j * 16 + l15) * 2048 +
                           (m0 & 2047) + wr * 64 + (quad * 4 + r) * 4) = o;
            }
    }
}

// ---------------- kernel 4: flash attention, 3-buffer counted-vmcnt K/V ----------------
// grid (24 slots, 32 b*h) x 256 threads (4 waves, 32 Q-rows each) = 768 blocks.
// s<8: whole qt=7-s. s in 8..15: qt=s half0. s in 16..23: qt=s-8 half1.
// K/V LDS: [64 row][64 col] row-major, 16B-chunk XOR swizzle cb^=row&7 applied
// on the GLOBAL SOURCE (gll16 dest linear) and on fragment reads.
// Pipeline: 2 tiles in flight, vmcnt(4)/iter (tile cur landed, next flying).
__global__ __launch_bounds__(256) void attn(const u16* __restrict__ qh, const u16* __restrict__ kh,
                                            const u16* __restrict__ vh, u16* __restrict__ ot,
                                            float* __restrict__ part, float* __restrict__ lp) {
    __shared__ u16 smem[33792];        // 67584 B -> 2 blocks/CU
    u16* sPQ = smem;                   // Q 128x64 (16 KB) aliased by sP strips (18432 B)
    // sK[i] = smem + 9216 + i*4096 ; sV[i] = smem + 21504 + i*4096  (u16 units)
    const int tid = threadIdx.x;
    const int lane = tid & 63, w = tid >> 6;
    const int quad = lane >> 4, l15 = lane & 15;
    const int s = blockIdx.x, by = blockIdx.y;
    int qt, j0, j1, half;
    if (s < 8)       { qt = 7 - s;  j0 = 0;      j1 = 2 * qt + 2; half = -1; }
    else if (s < 16) { qt = s;      j0 = 0;      j1 = qt + 1;     half = 0;  }
    else             { qt = s - 8;  j0 = qt + 1; j1 = 2 * qt + 2; half = 1;  }
    const int b = by >> 4, h = by & 15;
    // staging: chunk c in [0,512): row=c>>3, cb=c&7; content = global col-chunk cb^(row&7)
    const int row0 = tid >> 3;
    const int cb0 = (tid & 7) ^ (row0 & 7);            // (row0+32)&7 == row0&7 -> same cb for chunk1
    const u16* kg0 = kh + (b * 2048) * 1024 + h * 64 + row0 * 1024 + cb0 * 8;  // + jt*65536; +32768 chunk1
    const u16* vg0 = vh + (by * 64) * 2048 + row0 * 2048 + cb0 * 8;            // + jt*64;    +65536 chunk1
    const int fsw = (l15 & 7) * 8;                     // read-side XOR (u16 units), ^= per cb

    // Q: 128 rows x 64 e -> LDS (linear) -> registers
    const u16* qg = qh + (b * 2048 + qt * 128) * 1024 + h * 64;
#pragma unroll
    for (int p = 0; p < 4; ++p) {
        int c = p * 256 + tid;
        gll16(qg + (c >> 3) * 1024 + (c & 7) * 8, sPQ + c * 8);
    }
    __syncthreads();
    bf16x8 aq[2][2];
#pragma unroll
    for (int rg = 0; rg < 2; ++rg)
#pragma unroll
        for (int k2 = 0; k2 < 2; ++k2)
            aq[rg][k2] = *(const bf16x8*)(sPQ + (w * 32 + rg * 16 + l15) * 64 + k2 * 32 + quad * 8);

    // prologue: stage K/V tiles j0 (buf 0) and j0+1 (buf 1)
    {
        u16* sK0 = smem + 9216;
        u16* sV0 = smem + 21504;
        gll16(kg0 + j0 * 65536,         sK0 + tid * 8);
        gll16(kg0 + j0 * 65536 + 32768, sK0 + (256 + tid) * 8);
        gll16(vg0 + j0 * 64,            sV0 + tid * 8);
        gll16(vg0 + j0 * 64 + 65536,    sV0 + (256 + tid) * 8);
        if (j0 + 1 < j1) {
            u16* sK1 = sK0 + 4096;
            u16* sV1 = sV0 + 4096;
            gll16(kg0 + (j0 + 1) * 65536,         sK1 + tid * 8);
            gll16(kg0 + (j0 + 1) * 65536 + 32768, sK1 + (256 + tid) * 8);
            gll16(vg0 + (j0 + 1) * 64,            sV1 + tid * 8);
            gll16(vg0 + (j0 + 1) * 64 + 65536,    sV1 + (256 + tid) * 8);
        }
    }
    float lpart[2][4] = {};
    f32x4 oacc[2][4] = {};
    u16* sPw = sPQ + w * 2304;        // per-wave strip: 32 rows x 72 u16
    int cur = 0;
    for (int jt = j0; jt < j1; ++jt) {
        u16* sK = smem + 9216 + cur * 4096;
        u16* sV = smem + 21504 + cur * 4096;
        if (jt + 1 < j1) asm volatile("s_waitcnt vmcnt(4)" ::: "memory");  // tile cur landed
        else             asm volatile("s_waitcnt vmcnt(0)" ::: "memory");
        __builtin_amdgcn_s_barrier();                      // all waves done with buf cur+2
        if (jt + 2 < j1) {                                 // issue tile jt+2 (2 in flight)
            int nxt = cur + 2; if (nxt >= 3) nxt -= 3;
            u16* sKn = smem + 9216 + nxt * 4096;
            u16* sVn = smem + 21504 + nxt * 4096;
            gll16(kg0 + (jt + 2) * 65536,         sKn + tid * 8);
            gll16(kg0 + (jt + 2) * 65536 + 32768, sKn + (256 + tid) * 8);
            gll16(vg0 + (jt + 2) * 64,            sVn + tid * 8);
            gll16(vg0 + (jt + 2) * 64 + 65536,    sVn + (256 + tid) * 8);
        }
        f32x4 sacc[2][4] = {};
        __builtin_amdgcn_s_setprio(1);
#pragma unroll
        for (int j4 = 0; j4 < 4; ++j4)
#pragma unroll
            for (int k2 = 0; k2 < 2; ++k2) {
                bf16x8 bk = *(const bf16x8*)(sK + (j4 * 16 + l15) * 64 + (((k2 * 4 + quad) * 8) ^ fsw));
                sacc[0][j4] = __builtin_amdgcn_mfma_f32_16x16x32_bf16(aq[0][k2], bk, sacc[0][j4], 0, 0, 0);
                sacc[1][j4] = __builtin_amdgcn_mfma_f32_16x16x32_bf16(aq[1][k2], bk, sacc[1][j4], 0, 0, 0);
            }
        __builtin_amdgcn_s_setprio(0);
        if (jt >= 2 * qt) {        // diagonal tiles: causal mask (wave-uniform branch)
            int soff = (jt - 2 * qt) * 64;
#pragma unroll
            for (int rg = 0; rg < 2; ++rg)
#pragma unroll
                for (int j4 = 0; j4 < 4; ++j4)
#pragma unroll
                    for (int r = 0; r < 4; ++r) {
                        int sg = soff + j4 * 16 + l15;
                        int tg = w * 32 + rg * 16 + quad * 4 + r;
                        if (sg > tg) sacc[rg][j4][r] = -1e30f;
                    }
        }
        // exp2 -> tree-sum -> pack (cvt_pk) in one pass; kappa-packed P strip
#pragma unroll
        for (int rg = 0; rg < 2; ++rg)
#pragma unroll
            for (int r = 0; r < 4; ++r) {
                float p0 = __builtin_amdgcn_exp2f(sacc[rg][0][r]);
                float p1 = __builtin_amdgcn_exp2f(sacc[rg][1][r]);
                float p2 = __builtin_amdgcn_exp2f(sacc[rg][2][r]);
                float p3 = __builtin_amdgcn_exp2f(sacc[rg][3][r]);
                lpart[rg][r] += (p0 + p1) + (p2 + p3);
                bf16x4 o;
                o[0] = (__bf16)p0; o[1] = (__bf16)p1; o[2] = (__bf16)p2; o[3] = (__bf16)p3;
                *(bf16x4*)(sPw + (rg * 16 + quad * 4 + r) * 72 + l15 * 4) = o;
            }
        bf16x8 ap[2][2];
#pragma unroll
        for (int rg = 0; rg < 2; ++rg)
#pragma unroll
            for (int k2 = 0; k2 < 2; ++k2)
                ap[rg][k2] = *(const bf16x8*)(sPw + (rg * 16 + l15) * 72 + k2 * 32 + quad * 8);
        __builtin_amdgcn_s_setprio(1);
#pragma unroll
        for (int e4 = 0; e4 < 4; ++e4)
#pragma unroll
            for (int k2 = 0; k2 < 2; ++k2) {
                bf16x8 bv = *(const bf16x8*)(sV + (e4 * 16 + l15) * 64 + (((k2 * 4 + quad) * 8) ^ fsw));
                oacc[0][e4] = __builtin_amdgcn_mfma_f32_16x16x32_bf16(ap[0][k2], bv, oacc[0][e4], 0, 0, 0);
                oacc[1][e4] = __builtin_amdgcn_mfma_f32_16x16x32_bf16(ap[1][k2], bv, oacc[1][e4], 0, 0, 0);
            }
        __builtin_amdgcn_s_setprio(0);
        ++cur; if (cur == 3) cur = 0;
    }
    if (half < 0) {
        // whole block: reduce, normalize, store head-blocked [b][t][h*64+e]
#pragma unroll
        for (int rg = 0; rg < 2; ++rg)
#pragma unroll
            for (int r = 0; r < 4; ++r) {
                float rs = lpart[rg][r];
#pragma unroll
                for (int off = 1; off < 16; off <<= 1) rs += __shfl_xor(rs, off, 16);
                float inv = 1.f / rs;
                int t = qt * 128 + w * 32 + rg * 16 + quad * 4 + r;
                int base = (b * 2048 + t) * 1024 + h * 64;
#pragma unroll
                for (int e4 = 0; e4 < 4; ++e4)
                    ot[base + e4 * 16 + l15] = f2bf(oacc[rg][e4][r] * inv);
            }
    } else {
        // split block: store f32 partials (oacc rows + row-sums); consumed by gemm_out
        int pb = by * 8 + (qt - 8);
        float* pg = part + (pb * 2 + half) * 8192;
        float* lg = lp + pb * 256 + half * 128;
#pragma unroll
        for (int rg = 0; rg < 2; ++rg)
#pragma unroll
            for (int r = 0; r < 4; ++r) {
                float rs = lpart[rg][r];
#pragma unroll
                for (int off = 1; off < 16; off <<= 1) rs += __shfl_xor(rs, off, 16);
                int row = w * 32 + rg * 16 + quad * 4 + r;
                if (l15 == 0) lg[row] = rs;
#pragma unroll
                for (int e4 = 0; e4 < 4; ++e4)
                    pg[row * 64 + e4 * 16 + l15] = oacc[rg][e4][r];
            }
    }
}

// ---------------- kernel 5: out = ot/partials @ Wu + bu (combine fused) ----------------
// 256 blocks x 16 rows. Rows with qt<8 read bf16 ot; rows with qt>=8 read the
// f32 split partials + row-sums and normalize in-register (combine_o fused).
// Per block, b and qt are uniform (16-row granule never crosses a 128-row qt).
__global__ __launch_bounds__(256) void gemm_out(const u16* __restrict__ ot,
                                                const float* __restrict__ part,
                                                const float* __restrict__ lp,
                                                const u16* __restrict__ wut,
                                                const float* __restrict__ bu, float* __restrict__ out) {
    __shared__ float red[4][1088];     // [w][n*17 + m]
    int tid = threadIdx.x, lane = tid & 63, w = tid >> 6;
    int quad = lane >> 4, l15 = lane & 15;
    int m0 = blockIdx.x * 16;
    int b = m0 >> 11, t0 = m0 & 2047, qt = t0 >> 7;
    f32x4 acc[4] = {};
    const u16* bptr = wut + l15 * 1024 + w * 256 + quad * 8;
    if (qt < 8) {
        const u16* aptr = ot + (m0 + l15) * 1024 + w * 256 + quad * 8;
#pragma unroll
        for (int kk = 0; kk < 8; ++kk) {
            bf16x8 af = *(const bf16x8*)(aptr + kk * 32);
#pragma unroll
            for (int j = 0; j < 4; ++j) {
                bf16x8 bfr = *(const bf16x8*)(bptr + j * 16 * 1024 + kk * 32);
                acc[j] = __builtin_amdgcn_mfma_f32_16x16x32_bf16(af, bfr, acc[j], 0, 0, 0);
            }
        }
    } else {
        int rowp = (t0 & 127) + l15;           // row within the 128-row partial block
        float inv4[4];                          // per-head inv, h = w*4 + hh
#pragma unroll
        for (int hh = 0; hh < 4; ++hh) {
            int pb = (b * 16 + w * 4 + hh) * 8 + (qt - 8);
            inv4[hh] = 1.f / (lp[pb * 256 + rowp] + lp[pb * 256 + 128 + rowp]);
        }
#pragma unroll
        for (int kk = 0; kk < 8; ++kk) {
            const int hh = kk >> 1;             // compile-time under unroll
            int pb = (b * 16 + w * 4 + hh) * 8 + (qt - 8);
            int e = (kk & 1) * 32 + quad * 8;
            const float* pA = part + pb * 16384 + rowp * 64 + e;
            float4 a0 = *(const float4*)(pA);
            float4 a1 = *(const float4*)(pA + 4);
            float4 c0 = *(const float4*)(pA + 8192);
            float4 c1 = *(const float4*)(pA + 8192 + 4);
            float inv = inv4[hh];
            bf16x8 af;
            af[0] = (__bf16)((a0.x + c0.x) * inv); af[1] = (__bf16)((a0.y + c0.y) * inv);
            af[2] = (__bf16)((a0.z + c0.z) * inv); af[3] = (__bf16)((a0.w + c0.w) * inv);
            af[4] = (__bf16)((a1.x + c1.x) * inv); af[5] = (__bf16)((a1.y + c1.y) * inv);
            af[6] = (__bf16)((a1.z + c1.z) * inv); af[7] = (__bf16)((a1.w + c1.w) * inv);
#pragma unroll
            for (int j = 0; j < 4; ++j) {
                bf16x8 bfr = *(const bf16x8*)(bptr + j * 16 * 1024 + kk * 32);
                acc[j] = __builtin_amdgcn_mfma_f32_16x16x32_bf16(af, bfr, acc[j], 0, 0, 0);
            }
        }
    }
#pragma unroll
    for (int j = 0; j < 4; ++j)
#pragma unroll
        for (int r = 0; r < 4; ++r)
            red[w][(j * 16 + l15) * 17 + quad * 4 + r] = acc[j][r];
    __syncthreads();
    int n = tid & 63, mq = tid >> 6;
    float bias = bu[n];
#pragma unroll
    for (int i = 0; i < 4; ++i) {
        int m = mq * 4 + i;
        float s = red[0][n * 17 + m] + red[1][n * 17 + m] + red[2][n * 17 + m] + red[3][n * 17 + m];
        out[(m0 + m) * 64 + n] = s + bias;
    }
}

// ---------------- workspace layout (bytes) ----------------
#define OFF_XB   0u          /* 8 MB; ot aliases this (xb dead after gemm_qkv) */
#define OFF_WQT  8388608u    /* 2 MB */
#define OFF_WKT  10485760u
#define OFF_WVT  12582912u
#define OFF_WUT  14680064u   /* 128 KB */
#define OFF_QH   14811136u   /* 8 MB each */
#define OFF_KH   23199744u
#define OFF_VH   31588352u
#define OFF_OT   OFF_XB
#define OFF_PART 39976960u   /* 16 MB: 256 pairs x 2 x 128x64 f32 */
#define OFF_LP   56754176u   /* 256 KB: 256 x 256 f32 */

extern "C" void kernel_launch(void* const* d_in, const int* in_sizes, int n_in,
                              void* d_out, int out_size, void* d_ws, size_t ws_size,
                              hipStream_t stream) {
    (void)in_sizes; (void)n_in; (void)out_size; (void)ws_size;
    const float* inp = (const float*)d_in[0];
    // d_in[1] = causal mask — implemented analytically
    const float* Wq = (const float*)d_in[2];
    const float* Wk = (const float*)d_in[3];
    const float* Wv = (const float*)d_in[4];
    const float* Wu = (const float*)d_in[5];
    const float* bu = (const float*)d_in[6];
    float* out = (float*)d_out;
    char* ws = (char*)d_ws;
    u16* xb  = (u16*)(ws + OFF_XB);
    u16* wqt = (u16*)(ws + OFF_WQT);
    u16* wkt = (u16*)(ws + OFF_WKT);
    u16* wvt = (u16*)(ws + OFF_WVT);
    u16* wut = (u16*)(ws + OFF_WUT);
    u16* qh  = (u16*)(ws + OFF_QH);
    u16* kh  = (u16*)(ws + OFF_KH);
    u16* vh  = (u16*)(ws + OFF_VH);
    u16* ot  = (u16*)(ws + OFF_OT);
    float* part = (float*)(ws + OFF_PART);
    float* lpw  = (float*)(ws + OFF_LP);

    prep<<<8192, 256, 0, stream>>>(inp, xb, Wq, Wk, Wv, Wu, wqt, wkt, wvt, wut);
    gemm_qkv<<<dim3(32, 8, 3), 256, 0, stream>>>(xb, wqt, wkt, wvt, qh, kh, vh);
    attn<<<dim3(24, 32), 256, 0, stream>>>(qh, kh, vh, ot, part, lpw);
    gemm_out<<<256, 256, 0, stream>>>(ot, part, lpw, wut, bu, out);
}

// Round 12
// 159.843 us; speedup vs baseline: 1.0767x; 1.0767x over previous
//
#include <hip/hip_runtime.h>

// ---------------------------------------------------------------------------
// SelfAttention: B=2,T=2048,D_IN=1024,E=64,H=16, causal, interleaved (E,H)
// qh/kh: [b][t][h*64 + pi(e)] with pi(e)=(e&15)*4+(e>>4) applied to BOTH Q,K
//   (QK^T invariant). vh: [b][h][e][kappa(t)].
// gemm_qkv: 128x128 tile, 3-buffer counted-vmcnt pipeline, LINEAR LDS
//   (swizzle costs +4us in both regimes: rounds 3/10 — kept reverted).
// attn: 128-row Q tiles, 2-BUFFER vmcnt(0) K/V (51.2 KB -> 3 blocks/CU;
//   round 11 proved 3-buffer@2blk/CU loses ~9us: occupancy now load-bearing).
//   kappa-packed P, static-max softmax, 24-slot split grid; split partials
//   consumed directly by gemm_out (combine fused).
// ---------------------------------------------------------------------------

typedef __bf16 bf16x8 __attribute__((ext_vector_type(8)));
typedef __bf16 bf16x4 __attribute__((ext_vector_type(4)));
typedef float f32x4 __attribute__((ext_vector_type(4)));
typedef unsigned short u16;
typedef unsigned int u32;

#define AS1 __attribute__((address_space(1)))
#define AS3 __attribute__((address_space(3)))

__device__ __forceinline__ void gll16(const void* g, void* l) {
    __builtin_amdgcn_global_load_lds((const AS1 u32*)g, (AS3 u32*)l, 16, 0, 0);
}

__device__ __forceinline__ u16 f2bf(float f) {      // native cast (RNE, cvt_pk-pairable)
    __bf16 h = (__bf16)f;
    union { __bf16 h; u16 u; } v; v.h = h; return v.u;
}

#define MM 4096           // B*T
#define SCALE_LOG2E 0.18033688011112042f   // log2(e)/sqrt(64)

// ---------------- kernel 1: prep = cast_x (bid<4096) + transpose_w ----------------
__global__ void prep(const float* __restrict__ in, u16* __restrict__ out,
                     const float* __restrict__ Wq, const float* __restrict__ Wk,
                     const float* __restrict__ Wv, const float* __restrict__ Wu,
                     u16* __restrict__ wqt, u16* __restrict__ wkt,
                     u16* __restrict__ wvt, u16* __restrict__ wut) {
    __shared__ float lds[32][33];
    int bid = blockIdx.x, tid = threadIdx.x;
    if (bid < 4096) {                      // cast inp -> bf16, 1M float4
        int i = bid * 256 + tid;
        float4 f = ((const float4*)in)[i];
        bf16x4 o;
        o[0] = (__bf16)f.x; o[1] = (__bf16)f.y; o[2] = (__bf16)f.z; o[3] = (__bf16)f.w;
        ((bf16x4*)out)[i] = o;
        return;
    }
    int bid2 = bid - 4096;
    int z = bid2 >> 10, y = (bid2 >> 5) & 31, x = bid2 & 31;
    const float* src; u16* dst; int N;
    if (z == 0)      { src = Wq; dst = wqt; N = 1024; }
    else if (z == 1) { src = Wk; dst = wkt; N = 1024; }
    else if (z == 2) { src = Wv; dst = wvt; N = 1024; }
    else             { src = Wu; dst = wut; N = 64; if (y >= 2) return; }
    int k0 = x * 32, n0 = y * 32;
    int c = tid & 31, r0 = tid >> 5;
#pragma unroll
    for (int p = 0; p < 4; ++p) {
        int r = r0 + p * 8;
        lds[r][c] = src[(k0 + r) * N + n0 + c];
    }
    __syncthreads();
#pragma unroll
    for (int p = 0; p < 4; ++p) {
        int n = n0 + r0 + p * 8;
        if (z < 3) {
            int rnew = ((n & 15) << 6) | (n >> 4);
            dst[rnew * 1024 + k0 + c] = f2bf(lds[c][n - n0]);
        } else {
            int k = k0 + c;
            int kp = ((k & 15) << 6) | (k >> 4);       // h*64+e position
            dst[n * 1024 + kp] = f2bf(lds[c][n - n0]);
        }
    }
}

// ---------------- kernel 3: QKV GEMM, 3-buffer counted-vmcnt pipeline ----------------
// z=0: Q *SCALE -> [b][t][h*64+pi(e)]; z=1: K -> same (pi on both: S invariant);
// z=2: V -> [b][h][e][kappa(t)], kappa(u) = (u&15)*4 + (u>>4).
__global__ __launch_bounds__(256) void gemm_qkv(const u16* __restrict__ xb,
                                                const u16* __restrict__ wqt,
                                                const u16* __restrict__ wkt,
                                                const u16* __restrict__ wvt,
                                                u16* __restrict__ qh, u16* __restrict__ kh,
                                                u16* __restrict__ vh) {
    int z = blockIdx.z;
    const u16* wt = (z == 0) ? wqt : (z == 1) ? wkt : wvt;
    u16* dst      = (z == 0) ? qh  : (z == 1) ? kh  : vh;
    __shared__ u16 lA[3][128 * 32];
    __shared__ u16 lB[3][128 * 32];
    int tid = threadIdx.x;
    int m0 = blockIdx.x * 128, n0 = blockIdx.y * 128;
    int lane = tid & 63, w = tid >> 6;
    int wr = w >> 1, wc = w & 1;
    int l15 = lane & 15, quad = lane >> 4;
    f32x4 acc[4][4] = {};
    int srow = tid >> 2, scol = (tid & 3) * 8;
    const u16* ga = xb + (m0 + srow) * 1024 + scol;    // + pp*65536 + kb
    const u16* gb = wt + (n0 + srow) * 1024 + scol;
    // prologue: stage tiles 0 and 1
#pragma unroll
    for (int t0 = 0; t0 < 2; ++t0)
#pragma unroll
        for (int pp = 0; pp < 2; ++pp) {
            gll16(ga + pp * 65536 + t0 * 32, lA[t0] + (pp * 256 + tid) * 8);
            gll16(gb + pp * 65536 + t0 * 32, lB[t0] + (pp * 256 + tid) * 8);
        }
    int cur = 0;
#pragma unroll 1
    for (int kk = 0; kk < 32; ++kk) {
        if (kk < 31) asm volatile("s_waitcnt vmcnt(4)" ::: "memory");  // tile kk landed
        else         asm volatile("s_waitcnt vmcnt(0)" ::: "memory");
        __builtin_amdgcn_s_barrier();                  // all waves done with buf (kk+2)%3
        if (kk + 2 < 32) {                             // issue tile kk+2 (2 in flight)
            int nxt = cur + 2; if (nxt >= 3) nxt -= 3;
            int kb = (kk + 2) * 32;
#pragma unroll
            for (int pp = 0; pp < 2; ++pp) {
                gll16(ga + pp * 65536 + kb, lA[nxt] + (pp * 256 + tid) * 8);
                gll16(gb + pp * 65536 + kb, lB[nxt] + (pp * 256 + tid) * 8);
            }
        }
        bf16x8 af[4], bfr[4];
#pragma unroll
        for (int i = 0; i < 4; ++i)
            af[i] = *(const bf16x8*)(lA[cur] + (wr * 64 + i * 16 + l15) * 32 + quad * 8);
#pragma unroll
        for (int j = 0; j < 4; ++j)
            bfr[j] = *(const bf16x8*)(lB[cur] + (wc * 64 + j * 16 + l15) * 32 + quad * 8);
#pragma unroll
        for (int i = 0; i < 4; ++i)
#pragma unroll
            for (int j = 0; j < 4; ++j)
                acc[i][j] = __builtin_amdgcn_mfma_f32_16x16x32_bf16(af[i], bfr[j], acc[i][j], 0, 0, 0);
        ++cur; if (cur == 3) cur = 0;
    }
    int bb = m0 >> 11;
    int hb = (n0 >> 6) + wc;                   // head for this wave's n-half
    if (z < 2) {
        // pi-packed rows: column pi(j*16+l15) = l15*4+j -> bf16x4 per (i,r)
        float scale = (z == 0) ? SCALE_LOG2E : 1.f;
#pragma unroll
        for (int i = 0; i < 4; ++i)
#pragma unroll
            for (int r = 0; r < 4; ++r) {
                int m = m0 + wr * 64 + i * 16 + quad * 4 + r;
                bf16x4 o;
                o[0] = (__bf16)(acc[i][0][r] * scale); o[1] = (__bf16)(acc[i][1][r] * scale);
                o[2] = (__bf16)(acc[i][2][r] * scale); o[3] = (__bf16)(acc[i][3][r] * scale);
                *(bf16x4*)(dst + m * 1024 + hb * 64 + l15 * 4) = o;
            }
    } else {
        // kappa-packed V: pack i (t stride 16) -> contiguous kappa positions
#pragma unroll
        for (int j = 0; j < 4; ++j)
#pragma unroll
            for (int r = 0; r < 4; ++r) {
                bf16x4 o;
                o[0] = (__bf16)acc[0][j][r]; o[1] = (__bf16)acc[1][j][r];
                o[2] = (__bf16)acc[2][j][r]; o[3] = (__bf16)acc[3][j][r];
                *(bf16x4*)(dst + (((bb * 16 + hb) * 64) + j * 16 + l15) * 2048 +
                           (m0 & 2047) + wr * 64 + (quad * 4 + r) * 4) = o;
            }
    }
}

// ---------------- kernel 4: flash attention, gll16 double-buffered K/V ----------------
// grid (24 slots, 32 b*h) x 256 threads (4 waves, 32 Q-rows each) = 768 blocks.
// s<8: whole qt=7-s. s in 8..15: qt=s half0. s in 16..23: qt=s-8 half1.
// K/V LDS: [64 row][64 col] row-major, 16B-chunk XOR swizzle cb^=row&7 applied
// on the GLOBAL SOURCE (gll16 dest linear) and on fragment reads.
// 2 buffers, vmcnt(0)/iter: DMA for jt+1 in flight across all of jt's compute.
__global__ __launch_bounds__(256) void attn(const u16* __restrict__ qh, const u16* __restrict__ kh,
                                            const u16* __restrict__ vh, u16* __restrict__ ot,
                                            float* __restrict__ part, float* __restrict__ lp) {
    __shared__ u16 smem[25600];        // 51200 B -> 3 blocks/CU
    u16* sPQ = smem;                   // Q 128x64 (16 KB) aliased by sP strips (18432 B)
    // sK[cur] = smem + 9216 + cur*4096 ; sV[cur] = smem + 17408 + cur*4096
    const int tid = threadIdx.x;
    const int lane = tid & 63, w = tid >> 6;
    const int quad = lane >> 4, l15 = lane & 15;
    const int s = blockIdx.x, by = blockIdx.y;
    int qt, j0, j1, half;
    if (s < 8)       { qt = 7 - s;  j0 = 0;      j1 = 2 * qt + 2; half = -1; }
    else if (s < 16) { qt = s;      j0 = 0;      j1 = qt + 1;     half = 0;  }
    else             { qt = s - 8;  j0 = qt + 1; j1 = 2 * qt + 2; half = 1;  }
    const int b = by >> 4, h = by & 15;
    // staging: chunk c in [0,512): row=c>>3, cb=c&7; content = global col-chunk cb^(row&7)
    const int row0 = tid >> 3;
    const int cb0 = (tid & 7) ^ (row0 & 7);            // (row0+32)&7 == row0&7 -> same cb for chunk1
    const u16* kg0 = kh + (b * 2048) * 1024 + h * 64 + row0 * 1024 + cb0 * 8;  // + jt*65536; +32768 chunk1
    const u16* vg0 = vh + (by * 64) * 2048 + row0 * 2048 + cb0 * 8;            // + jt*64;    +65536 chunk1
    const int fsw = (l15 & 7) * 8;                     // read-side XOR (u16 units), ^= per cb

    // Q: 128 rows x 64 e -> LDS (linear) -> registers
    const u16* qg = qh + (b * 2048 + qt * 128) * 1024 + h * 64;
#pragma unroll
    for (int p = 0; p < 4; ++p) {
        int c = p * 256 + tid;
        gll16(qg + (c >> 3) * 1024 + (c & 7) * 8, sPQ + c * 8);
    }
    __syncthreads();
    bf16x8 aq[2][2];
#pragma unroll
    for (int rg = 0; rg < 2; ++rg)
#pragma unroll
        for (int k2 = 0; k2 < 2; ++k2)
            aq[rg][k2] = *(const bf16x8*)(sPQ + (w * 32 + rg * 16 + l15) * 64 + k2 * 32 + quad * 8);

    // prologue: stage K/V tile j0 into buffer 0
    {
        u16* sK0 = smem + 9216;
        u16* sV0 = smem + 17408;
        gll16(kg0 + j0 * 65536,         sK0 + tid * 8);
        gll16(kg0 + j0 * 65536 + 32768, sK0 + (256 + tid) * 8);
        gll16(vg0 + j0 * 64,            sV0 + tid * 8);
        gll16(vg0 + j0 * 64 + 65536,    sV0 + (256 + tid) * 8);
    }
    float lpart[2][4] = {};
    f32x4 oacc[2][4] = {};
    u16* sPw = sPQ + w * 2304;        // per-wave strip: 32 rows x 72 u16
    for (int jt = j0; jt < j1; ++jt) {
        int cur = (jt - j0) & 1;
        u16* sK = smem + 9216 + cur * 4096;
        u16* sV = smem + 17408 + cur * 4096;
        asm volatile("s_waitcnt vmcnt(0)" ::: "memory");   // cur-tile DMA landed
        __builtin_amdgcn_s_barrier();                      // all waves done with prev buf
        if (jt + 1 < j1) {                                 // DMA next tile, overlaps compute
            u16* sKn = smem + 9216 + (cur ^ 1) * 4096;
            u16* sVn = smem + 17408 + (cur ^ 1) * 4096;
            gll16(kg0 + (jt + 1) * 65536,         sKn + tid * 8);
            gll16(kg0 + (jt + 1) * 65536 + 32768, sKn + (256 + tid) * 8);
            gll16(vg0 + (jt + 1) * 64,            sVn + tid * 8);
            gll16(vg0 + (jt + 1) * 64 + 65536,    sVn + (256 + tid) * 8);
        }
        f32x4 sacc[2][4] = {};
        __builtin_amdgcn_s_setprio(1);
#pragma unroll
        for (int j4 = 0; j4 < 4; ++j4)
#pragma unroll
            for (int k2 = 0; k2 < 2; ++k2) {
                bf16x8 bk = *(const bf16x8*)(sK + (j4 * 16 + l15) * 64 + (((k2 * 4 + quad) * 8) ^ fsw));
                sacc[0][j4] = __builtin_amdgcn_mfma_f32_16x16x32_bf16(aq[0][k2], bk, sacc[0][j4], 0, 0, 0);
                sacc[1][j4] = __builtin_amdgcn_mfma_f32_16x16x32_bf16(aq[1][k2], bk, sacc[1][j4], 0, 0, 0);
            }
        __builtin_amdgcn_s_setprio(0);
        if (jt >= 2 * qt) {        // diagonal tiles: causal mask (wave-uniform branch)
            int soff = (jt - 2 * qt) * 64;
#pragma unroll
            for (int rg = 0; rg < 2; ++rg)
#pragma unroll
                for (int j4 = 0; j4 < 4; ++j4)
#pragma unroll
                    for (int r = 0; r < 4; ++r) {
                        int sg = soff + j4 * 16 + l15;
                        int tg = w * 32 + rg * 16 + quad * 4 + r;
                        if (sg > tg) sacc[rg][j4][r] = -1e30f;
                    }
        }
        // exp2 -> tree-sum -> pack (cvt_pk) in one pass; kappa-packed P strip
#pragma unroll
        for (int rg = 0; rg < 2; ++rg)
#pragma unroll
            for (int r = 0; r < 4; ++r) {
                float p0 = __builtin_amdgcn_exp2f(sacc[rg][0][r]);
                float p1 = __builtin_amdgcn_exp2f(sacc[rg][1][r]);
                float p2 = __builtin_amdgcn_exp2f(sacc[rg][2][r]);
                float p3 = __builtin_amdgcn_exp2f(sacc[rg][3][r]);
                lpart[rg][r] += (p0 + p1) + (p2 + p3);
                bf16x4 o;
                o[0] = (__bf16)p0; o[1] = (__bf16)p1; o[2] = (__bf16)p2; o[3] = (__bf16)p3;
                *(bf16x4*)(sPw + (rg * 16 + quad * 4 + r) * 72 + l15 * 4) = o;
            }
        bf16x8 ap[2][2];
#pragma unroll
        for (int rg = 0; rg < 2; ++rg)
#pragma unroll
            for (int k2 = 0; k2 < 2; ++k2)
                ap[rg][k2] = *(const bf16x8*)(sPw + (rg * 16 + l15) * 72 + k2 * 32 + quad * 8);
        __builtin_amdgcn_s_setprio(1);
#pragma unroll
        for (int e4 = 0; e4 < 4; ++e4)
#pragma unroll
            for (int k2 = 0; k2 < 2; ++k2) {
                bf16x8 bv = *(const bf16x8*)(sV + (e4 * 16 + l15) * 64 + (((k2 * 4 + quad) * 8) ^ fsw));
                oacc[0][e4] = __builtin_amdgcn_mfma_f32_16x16x32_bf16(ap[0][k2], bv, oacc[0][e4], 0, 0, 0);
                oacc[1][e4] = __builtin_amdgcn_mfma_f32_16x16x32_bf16(ap[1][k2], bv, oacc[1][e4], 0, 0, 0);
            }
        __builtin_amdgcn_s_setprio(0);
    }
    if (half < 0) {
        // whole block: reduce, normalize, store head-blocked [b][t][h*64+e]
#pragma unroll
        for (int rg = 0; rg < 2; ++rg)
#pragma unroll
            for (int r = 0; r < 4; ++r) {
                float rs = lpart[rg][r];
#pragma unroll
                for (int off = 1; off < 16; off <<= 1) rs += __shfl_xor(rs, off, 16);
                float inv = 1.f / rs;
                int t = qt * 128 + w * 32 + rg * 16 + quad * 4 + r;
                int base = (b * 2048 + t) * 1024 + h * 64;
#pragma unroll
                for (int e4 = 0; e4 < 4; ++e4)
                    ot[base + e4 * 16 + l15] = f2bf(oacc[rg][e4][r] * inv);
            }
    } else {
        // split block: store f32 partials (oacc rows + row-sums); consumed by gemm_out
        int pb = by * 8 + (qt - 8);
        float* pg = part + (pb * 2 + half) * 8192;
        float* lg = lp + pb * 256 + half * 128;
#pragma unroll
        for (int rg = 0; rg < 2; ++rg)
#pragma unroll
            for (int r = 0; r < 4; ++r) {
                float rs = lpart[rg][r];
#pragma unroll
                for (int off = 1; off < 16; off <<= 1) rs += __shfl_xor(rs, off, 16);
                int row = w * 32 + rg * 16 + quad * 4 + r;
                if (l15 == 0) lg[row] = rs;
#pragma unroll
                for (int e4 = 0; e4 < 4; ++e4)
                    pg[row * 64 + e4 * 16 + l15] = oacc[rg][e4][r];
            }
    }
}

// ---------------- kernel 5: out = ot/partials @ Wu + bu (combine fused) ----------------
// 256 blocks x 16 rows. Rows with qt<8 read bf16 ot; rows with qt>=8 read the
// f32 split partials + row-sums and normalize in-register (combine_o fused).
// Per block, b and qt are uniform (16-row granule never crosses a 128-row qt).
__global__ __launch_bounds__(256) void gemm_out(const u16* __restrict__ ot,
                                                const float* __restrict__ part,
                                                const float* __restrict__ lp,
                                                const u16* __restrict__ wut,
                                                const float* __restrict__ bu, float* __restrict__ out) {
    __shared__ float red[4][1088];     // [w][n*17 + m]
    int tid = threadIdx.x, lane = tid & 63, w = tid >> 6;
    int quad = lane >> 4, l15 = lane & 15;
    int m0 = blockIdx.x * 16;
    int b = m0 >> 11, t0 = m0 & 2047, qt = t0 >> 7;
    f32x4 acc[4] = {};
    const u16* bptr = wut + l15 * 1024 + w * 256 + quad * 8;
    if (qt < 8) {
        const u16* aptr = ot + (m0 + l15) * 1024 + w * 256 + quad * 8;
#pragma unroll
        for (int kk = 0; kk < 8; ++kk) {
            bf16x8 af = *(const bf16x8*)(aptr + kk * 32);
#pragma unroll
            for (int j = 0; j < 4; ++j) {
                bf16x8 bfr = *(const bf16x8*)(bptr + j * 16 * 1024 + kk * 32);
                acc[j] = __builtin_amdgcn_mfma_f32_16x16x32_bf16(af, bfr, acc[j], 0, 0, 0);
            }
        }
    } else {
        int rowp = (t0 & 127) + l15;           // row within the 128-row partial block
        float inv4[4];                          // per-head inv, h = w*4 + hh
#pragma unroll
        for (int hh = 0; hh < 4; ++hh) {
            int pb = (b * 16 + w * 4 + hh) * 8 + (qt - 8);
            inv4[hh] = 1.f / (lp[pb * 256 + rowp] + lp[pb * 256 + 128 + rowp]);
        }
#pragma unroll
        for (int kk = 0; kk < 8; ++kk) {
            const int hh = kk >> 1;             // compile-time under unroll
            int pb = (b * 16 + w * 4 + hh) * 8 + (qt - 8);
            int e = (kk & 1) * 32 + quad * 8;
            const float* pA = part + pb * 16384 + rowp * 64 + e;
            float4 a0 = *(const float4*)(pA);
            float4 a1 = *(const float4*)(pA + 4);
            float4 c0 = *(const float4*)(pA + 8192);
            float4 c1 = *(const float4*)(pA + 8192 + 4);
            float inv = inv4[hh];
            bf16x8 af;
            af[0] = (__bf16)((a0.x + c0.x) * inv); af[1] = (__bf16)((a0.y + c0.y) * inv);
            af[2] = (__bf16)((a0.z + c0.z) * inv); af[3] = (__bf16)((a0.w + c0.w) * inv);
            af[4] = (__bf16)((a1.x + c1.x) * inv); af[5] = (__bf16)((a1.y + c1.y) * inv);
            af[6] = (__bf16)((a1.z + c1.z) * inv); af[7] = (__bf16)((a1.w + c1.w) * inv);
#pragma unroll
            for (int j = 0; j < 4; ++j) {
                bf16x8 bfr = *(const bf16x8*)(bptr + j * 16 * 1024 + kk * 32);
                acc[j] = __builtin_amdgcn_mfma_f32_16x16x32_bf16(af, bfr, acc[j], 0, 0, 0);
            }
        }
    }
#pragma unroll
    for (int j = 0; j < 4; ++j)
#pragma unroll
        for (int r = 0; r < 4; ++r)
            red[w][(j * 16 + l15) * 17 + quad * 4 + r] = acc[j][r];
    __syncthreads();
    int n = tid & 63, mq = tid >> 6;
    float bias = bu[n];
#pragma unroll
    for (int i = 0; i < 4; ++i) {
        int m = mq * 4 + i;
        float s = red[0][n * 17 + m] + red[1][n * 17 + m] + red[2][n * 17 + m] + red[3][n * 17 + m];
        out[(m0 + m) * 64 + n] = s + bias;
    }
}

// ---------------- workspace layout (bytes) ----------------
#define OFF_XB   0u          /* 8 MB; ot aliases this (xb dead after gemm_qkv) */
#define OFF_WQT  8388608u    /* 2 MB */
#define OFF_WKT  10485760u
#define OFF_WVT  12582912u
#define OFF_WUT  14680064u   /* 128 KB */
#define OFF_QH   14811136u   /* 8 MB each */
#define OFF_KH   23199744u
#define OFF_VH   31588352u
#define OFF_OT   OFF_XB
#define OFF_PART 39976960u   /* 16 MB: 256 pairs x 2 x 128x64 f32 */
#define OFF_LP   56754176u   /* 256 KB: 256 x 256 f32 */

extern "C" void kernel_launch(void* const* d_in, const int* in_sizes, int n_in,
                              void* d_out, int out_size, void* d_ws, size_t ws_size,
                              hipStream_t stream) {
    (void)in_sizes; (void)n_in; (void)out_size; (void)ws_size;
    const float* inp = (const float*)d_in[0];
    // d_in[1] = causal mask — implemented analytically
    const float* Wq = (const float*)d_in[2];
    const float* Wk = (const float*)d_in[3];
    const float* Wv = (const float*)d_in[4];
    const float* Wu = (const float*)d_in[5];
    const float* bu = (const float*)d_in[6];
    float* out = (float*)d_out;
    char* ws = (char*)d_ws;
    u16* xb  = (u16*)(ws + OFF_XB);
    u16* wqt = (u16*)(ws + OFF_WQT);
    u16* wkt = (u16*)(ws + OFF_WKT);
    u16* wvt = (u16*)(ws + OFF_WVT);
    u16* wut = (u16*)(ws + OFF_WUT);
    u16* qh  = (u16*)(ws + OFF_QH);
    u16* kh  = (u16*)(ws + OFF_KH);
    u16* vh  = (u16*)(ws + OFF_VH);
    u16* ot  = (u16*)(ws + OFF_OT);
    float* part = (float*)(ws + OFF_PART);
    float* lpw  = (float*)(ws + OFF_LP);

    prep<<<8192, 256, 0, stream>>>(inp, xb, Wq, Wk, Wv, Wu, wqt, wkt, wvt, wut);
    gemm_qkv<<<dim3(32, 8, 3), 256, 0, stream>>>(xb, wqt, wkt, wvt, qh, kh, vh);
    attn<<<dim3(24, 32), 256, 0, stream>>>(qh, kh, vh, ot, part, lpw);
    gemm_out<<<256, 256, 0, stream>>>(ot, part, lpw, wut, bu, out);
}